// Round 16
// baseline (493.359 us; speedup 1.0000x reference)
//
#include <hip/hip_runtime.h>
#include <cstdint>
#include <cstddef>

#define M_DIM 4096
#define N_DIM 16384
#define K_DIM 4096
#define NBLK_Q 128

#define BM 128
#define BN 128
#define BK 64
#define KTILES (K_DIM / BK)  // 64
#define BUFB 8192            // A slab only: [ks 2][m32 4][1KB]
#define NBUF 2               // 16 KB LDS per block

typedef int i32x4 __attribute__((ext_vector_type(4)));
typedef int i32x16 __attribute__((ext_vector_type(16)));

#define SFENCE() __builtin_amdgcn_sched_barrier(0)
#define BAR() __builtin_amdgcn_s_barrier()
#define WAITVM(n) asm volatile("s_waitcnt vmcnt(" #n ")")
#define WAITLG0() asm volatile("s_waitcnt lgkmcnt(0)")

// ---- pre-pass 1: per-row int8 quant of x, staged-tile order ----
// A8S = [mtile256 16][k32 128][m32 8][kg 2][row 32][16B]
__global__ __launch_bounds__(256) void quant_x(const float* __restrict__ x,
                                               char* __restrict__ A8S,
                                               float* __restrict__ sxr) {
  const int m = blockIdx.x;
  const int t = threadIdx.x;
  const float* xr = x + (size_t)m * K_DIM + t * 16;
  float4 v[4];
#pragma unroll
  for (int i = 0; i < 4; ++i) v[i] = ((const float4*)xr)[i];
  float amax = 0.f;
#pragma unroll
  for (int i = 0; i < 4; ++i)
    amax = fmaxf(amax, fmaxf(fmaxf(fabsf(v[i].x), fabsf(v[i].y)),
                             fmaxf(fabsf(v[i].z), fabsf(v[i].w))));
#pragma unroll
  for (int off = 32; off; off >>= 1) amax = fmaxf(amax, __shfl_xor(amax, off, 64));
  __shared__ float wmax[4];
  if ((t & 63) == 0) wmax[t >> 6] = amax;
  __syncthreads();
  amax = fmaxf(fmaxf(wmax[0], wmax[1]), fmaxf(wmax[2], wmax[3]));
  const float inv = 127.0f / amax;
  if (t == 0) sxr[m] = amax / 127.0f;
  unsigned d[4];
#pragma unroll
  for (int i = 0; i < 4; ++i) {
    int q0 = (int)rintf(v[i].x * inv), q1 = (int)rintf(v[i].y * inv);
    int q2 = (int)rintf(v[i].z * inv), q3 = (int)rintf(v[i].w * inv);
    d[i] = (q0 & 0xff) | ((q1 & 0xff) << 8) | ((q2 & 0xff) << 16) | ((q3 & 0xff) << 24);
  }
  const int k32 = t >> 1, kg = t & 1;
  const int mtile = m >> 8, mm = m & 255, m32 = mm >> 5, r = mm & 31;
  int4* dst = (int4*)(A8S + ((size_t)(mtile * 128 + k32)) * 8192 + m32 * 1024 + kg * 512 + r * 16);
  *dst = make_int4(d[0], d[1], d[2], d[3]);
}

// ---- pre-pass 2: W requant to per-column scale, staged-tile order ----
// B8S = [ntile256 64][k32 128][n32 8][kg 2][col 32][16B]
__global__ __launch_bounds__(256) void pack_w8(const int* __restrict__ qs,
                                               const float* __restrict__ scales,
                                               char* __restrict__ B8S,
                                               float* __restrict__ swc) {
  const int o = blockIdx.x * 4 + (threadIdx.x >> 6);
  const int l = threadIdx.x & 63;
  const float s0 = scales[(size_t)o * NBLK_Q + l];
  const float s1 = scales[(size_t)o * NBLK_Q + 64 + l];
  float S = fmaxf(s0, s1);
#pragma unroll
  for (int off = 32; off; off >>= 1) S = fmaxf(S, __shfl_xor(S, off, 64));
  if (l == 0) swc[o] = S;
  const float rS = 1.0f / S;
  const int nt = o >> 8, col = o & 255, n32 = col >> 5, c = col & 31;
#pragma unroll
  for (int h = 0; h < 2; ++h) {
    const int nb = l + 64 * h;
    const float ratio = ((h == 0) ? s0 : s1) * rS;
    const int4* q = (const int4*)(qs + ((size_t)o * NBLK_Q + nb) * 32);
    unsigned d[8];
#pragma unroll
    for (int g = 0; g < 8; ++g) {
      int4 v = q[g];
      int a0 = (int)rintf((float)v.x * ratio);
      int a1 = (int)rintf((float)v.y * ratio);
      int a2 = (int)rintf((float)v.z * ratio);
      int a3 = (int)rintf((float)v.w * ratio);
      d[g] = (a0 & 0xff) | ((a1 & 0xff) << 8) | ((a2 & 0xff) << 16) | ((a3 & 0xff) << 24);
    }
    char* dst = B8S + ((size_t)(nt * 128 + nb)) * 8192 + n32 * 1024 + c * 16;
    ((int4*)dst)[0] = make_int4(d[0], d[1], d[2], d[3]);
    ((int4*)(dst + 512))[0] = make_int4(d[4], d[5], d[6], d[7]);
  }
}

// ---- main GEMM: 128x128 tile, 4 waves, B L2->reg direct, A via 16KB LDS ----
// 3 independent blocks/CU (launch_bounds(256,3)): cross-block TLP covers
// lgkm/vmem stalls (m114) — the mechanism R12/R15's single-block lockstep
// lacked. Per-wave 64x64 = 2x2 of 32x32, acc 64 VGPR. B-frags ARE the staged
// regs (B8S staged order: 1KB coalesced per frag, addr = base + l*16) -> zero
// B LDS traffic. Per tile: DS = 4 read + 2 write per thread (24 instr/block);
// MFMA 8/wave; VMEM 6 (B(kt+1)x4, A(kt+2)x2).
// CADENCE (fixed 6 loads/tile, clamped tail -> dups land in dead buffers):
//   top: queue=[B(kt)x4, A(kt+1)x2] -> WAITVM(2) lands B(kt) exactly.
//   post-MFMA: queue=[A(kt+1)2, B(kt+1)4, A(kt+2)2]=8 -> WAITVM(6) lands
//   A(kt+1) exactly -> ds_write into buf (kt+1)&1 (other buf; its last reads
//   were tile kt-1, lgkm0'd before that tile's barrier). vmcnt never 0.
// Grid: 4096 blocks; XCD partition: mt = xcd*4+(k&3), nt = k>>2 -> per-XCD
// A-band 2MB L2-resident; 4 consecutive blocks share each B-tile; B8S (64MB)
// L3-resident (FETCH stays ~300MB).
__global__ __launch_bounds__(256, 3) void gemm_i8(
    const char* __restrict__ A8S, const char* __restrict__ B8S,
    const float* __restrict__ sxr, const float* __restrict__ swc,
    const float* __restrict__ bias, float* __restrict__ C) {
  __shared__ __align__(16) char lds[NBUF * BUFB];  // 16 KB

  const int tid = threadIdx.x;
  const int w = tid >> 6;   // wave 0..3
  const int l = tid & 63;
  const int wm = w >> 1;    // 0..1 (M half)
  const int wn = w & 1;     // 0..1 (N half)

  const int bid = blockIdx.x;
  const int xcd = bid & 7;
  const int kk = bid >> 3;            // 0..511
  const int mt = xcd * 4 + (kk & 3);  // 0..31
  const int nt = kk >> 2;             // 0..127
  const int brow = mt * BM;

  // staging sources (all 1KB-contiguous per wave-instr)
  const char* srcA = A8S + (size_t)(mt >> 1) * 1048576 + (size_t)(mt & 1) * 4096
                     + w * 1024 + l * 16;
  const char* srcB0 = B8S + (size_t)(nt >> 1) * 1048576
                      + (size_t)((nt & 1) * 4 + wn * 2) * 1024 + l * 16;
  const char* srcB1 = srcB0 + 1024;
  const int doff = w * 1024 + l * 16;          // A-stage LDS dest (per ks +4096)
  const int rA = (wm * 2) * 1024 + l * 16;     // A-frag base (i: +1024, ks: +4096)

  i32x16 acc[2][2] = {};
  i32x4 aa00, aa01, aa10, aa11;                 // A-frags (s,i) for current tile
  i32x4 bc00, bc01, bc10, bc11;                 // B cur (s,j)
  i32x4 bn00, bn01, bn10, bn11;                 // B next (in flight)
  i32x4 aC0, aC1, aN0, aN1;                     // A-stage cur / next

  // ---- prologue: A(0)->buf0; Bcur=B(0); Acur=A(1); queue = 6 ----
  {
    aN0 = *(const i32x4*)(srcA);            // A(0) ks0
    aN1 = *(const i32x4*)(srcA + 8192);     // A(0) ks1
    WAITVM(0);
    *(i32x4*)(lds + doff) = aN0;
    *(i32x4*)(lds + 4096 + doff) = aN1;
    bc00 = *(const i32x4*)(srcB0);          // B(0) s0 j0
    bc01 = *(const i32x4*)(srcB1);          // B(0) s0 j1
    bc10 = *(const i32x4*)(srcB0 + 8192);   // B(0) s1 j0
    bc11 = *(const i32x4*)(srcB1 + 8192);   // B(0) s1 j1
    aC0 = *(const i32x4*)(srcA + 2 * 8192); // A(1) ks0
    aC1 = *(const i32x4*)(srcA + 3 * 8192); // A(1) ks1
    WAITLG0();
    SFENCE(); BAR(); SFENCE();
  }

#define TILE(KT, BC00, BC01, BC10, BC11, BN00, BN01, BN10, BN11, AC0, AC1, AN0, AN1) \
  do {                                                                         \
    WAITVM(2); /* B(KT) landed; A(KT+1) may fly */                             \
    const char* bb = lds + ((KT) & 1) * BUFB;                                  \
    aa00 = *(const i32x4*)(bb + rA);                                           \
    aa01 = *(const i32x4*)(bb + rA + 1024);                                    \
    aa10 = *(const i32x4*)(bb + 4096 + rA);                                    \
    aa11 = *(const i32x4*)(bb + 4096 + rA + 1024);                             \
    {                                                                          \
      const int qb = ((KT) + 1 > KTILES - 1) ? (KTILES - 1) : ((KT) + 1);      \
      const size_t ob = (size_t)qb * 16384;                                    \
      BN00 = *(const i32x4*)(srcB0 + ob);                                      \
      BN01 = *(const i32x4*)(srcB1 + ob);                                      \
      BN10 = *(const i32x4*)(srcB0 + ob + 8192);                               \
      BN11 = *(const i32x4*)(srcB1 + ob + 8192);                               \
      const int qa = ((KT) + 2 > KTILES - 1) ? (KTILES - 1) : ((KT) + 2);      \
      AN0 = *(const i32x4*)(srcA + (size_t)qa * 16384);                        \
      AN1 = *(const i32x4*)(srcA + (size_t)qa * 16384 + 8192);                 \
    }                                                                          \
    WAITLG0(); /* A-frags ready */                                             \
    SFENCE();                                                                  \
    __builtin_amdgcn_s_setprio(1);                                             \
    acc[0][0] = __builtin_amdgcn_mfma_i32_32x32x32_i8(aa00, BC00, acc[0][0], 0, 0, 0); \
    acc[0][1] = __builtin_amdgcn_mfma_i32_32x32x32_i8(aa00, BC01, acc[0][1], 0, 0, 0); \
    acc[1][0] = __builtin_amdgcn_mfma_i32_32x32x32_i8(aa01, BC00, acc[1][0], 0, 0, 0); \
    acc[1][1] = __builtin_amdgcn_mfma_i32_32x32x32_i8(aa01, BC01, acc[1][1], 0, 0, 0); \
    acc[0][0] = __builtin_amdgcn_mfma_i32_32x32x32_i8(aa10, BC10, acc[0][0], 0, 0, 0); \
    acc[0][1] = __builtin_amdgcn_mfma_i32_32x32x32_i8(aa10, BC11, acc[0][1], 0, 0, 0); \
    acc[1][0] = __builtin_amdgcn_mfma_i32_32x32x32_i8(aa11, BC10, acc[1][0], 0, 0, 0); \
    acc[1][1] = __builtin_amdgcn_mfma_i32_32x32x32_i8(aa11, BC11, acc[1][1], 0, 0, 0); \
    __builtin_amdgcn_s_setprio(0);                                             \
    SFENCE();                                                                  \
    WAITVM(6); /* A(KT+1) landed; 6 newest (B(KT+1),A(KT+2)) fly */            \
    {                                                                          \
      char* nb = lds + (((KT) + 1) & 1) * BUFB;                                \
      *(i32x4*)(nb + doff) = AC0;                                              \
      *(i32x4*)(nb + 4096 + doff) = AC1;                                       \
    }                                                                          \
    SFENCE();                                                                  \
    WAITLG0();                                                                 \
    SFENCE(); BAR(); SFENCE();                                                 \
  } while (0)

  for (int kt = 0; kt < KTILES; kt += 2) {
    TILE(kt, bc00, bc01, bc10, bc11, bn00, bn01, bn10, bn11, aC0, aC1, aN0, aN1);
    TILE(kt + 1, bn00, bn01, bn10, bn11, bc00, bc01, bc10, bc11, aN0, aN1, aC0, aC1);
  }
#undef TILE

  WAITVM(0);
  SFENCE();

  // epilogue: 32x32 C/D layout col = lane&31, row = (reg&3)+8*(reg>>2)+4*(lane>>5)
#pragma unroll
  for (int i = 0; i < 2; ++i) {
    const int rbx = brow + wm * 64 + i * 32 + 4 * (l >> 5);
#pragma unroll
    for (int j = 0; j < 2; ++j) {
      const int col = nt * 128 + (wn * 2 + j) * 32 + (l & 31);
      const float Sw = swc[col];
      const float bv = bias[col];
#pragma unroll
      for (int r = 0; r < 16; ++r) {
        const int row = rbx + (r & 3) + 8 * (r >> 2);
        C[(size_t)row * N_DIM + col] = (float)acc[i][j][r] * (sxr[row] * Sw) + bv;
      }
    }
  }
}

// ---- fallback (ws too small): exact fp32, slow but correct ----
__global__ void naive_gemm(const float* __restrict__ x, const int* __restrict__ qs,
                           const float* __restrict__ scales, const float* __restrict__ bias,
                           float* __restrict__ y) {
  size_t idx = (size_t)blockIdx.x * 256 + threadIdx.x;
  if (idx >= (size_t)M_DIM * N_DIM) return;
  int o = (int)(idx % N_DIM);
  size_t m = idx / N_DIM;
  const float* xr = x + m * K_DIM;
  const int* q = qs + (size_t)o * K_DIM;
  const float* sc = scales + (size_t)o * NBLK_Q;
  float sum = 0.f;
  for (int nb = 0; nb < NBLK_Q; ++nb) {
    float s = sc[nb];
    float bs = 0.f;
#pragma unroll 8
    for (int b = 0; b < 32; ++b) bs += xr[nb * 32 + b] * (float)q[nb * 32 + b];
    sum += s * bs;
  }
  y[idx] = sum + bias[o];
}

extern "C" void kernel_launch(void* const* d_in, const int* in_sizes, int n_in,
                              void* d_out, int out_size, void* d_ws, size_t ws_size,
                              hipStream_t stream) {
  const float* x = (const float*)d_in[0];
  const int* qs = (const int*)d_in[1];
  const float* scales = (const float*)d_in[2];
  const float* bias = (const float*)d_in[3];
  float* y = (float*)d_out;

  const size_t A8_bytes = (size_t)M_DIM * K_DIM;   // 16 MB
  const size_t B8_bytes = (size_t)N_DIM * K_DIM;   // 64 MB
  const size_t SX_bytes = (size_t)M_DIM * 4;
  const size_t SW_bytes = (size_t)N_DIM * 4;

  if (ws_size < A8_bytes + B8_bytes + SX_bytes + SW_bytes) {
    size_t total = (size_t)M_DIM * N_DIM;
    naive_gemm<<<(unsigned)((total + 255) / 256), 256, 0, stream>>>(x, qs, scales, bias, y);
    return;
  }

  char* A8S = (char*)d_ws;
  char* B8S = A8S + A8_bytes;
  float* sxr = (float*)(B8S + B8_bytes);
  float* swc = (float*)((char*)sxr + SX_bytes);

  quant_x<<<M_DIM, 256, 0, stream>>>(x, A8S, sxr);
  pack_w8<<<N_DIM / 4, 256, 0, stream>>>(qs, scales, B8S, swc);
  gemm_i8<<<(M_DIM / BM) * (N_DIM / BN), 256, 0, stream>>>(A8S, B8S, sxr, swc, bias, y);
}

// Round 17
// 459.784 us; speedup vs baseline: 1.0730x; 1.0730x over previous
//
#include <hip/hip_runtime.h>
#include <cstdint>
#include <cstddef>

#define M_DIM 4096
#define N_DIM 16384
#define K_DIM 4096
#define NBLK_Q 128

#define BM 256
#define BN 256
#define BK 32
#define KSTEPS (K_DIM / BK)  // 128

typedef int i32x4 __attribute__((ext_vector_type(4)));
typedef int i32x16 __attribute__((ext_vector_type(16)));

#define SFENCE() __builtin_amdgcn_sched_barrier(0)
#define WAITVM(n) asm volatile("s_waitcnt vmcnt(" #n ")")

// ---- pre-pass 1: per-row int8 quant of x, staged-tile order ----
// A8S = [mtile256 16][k32 128][m32 8][kg 2][row 32][16B]
__global__ __launch_bounds__(256) void quant_x(const float* __restrict__ x,
                                               char* __restrict__ A8S,
                                               float* __restrict__ sxr) {
  const int m = blockIdx.x;
  const int t = threadIdx.x;
  const float* xr = x + (size_t)m * K_DIM + t * 16;
  float4 v[4];
#pragma unroll
  for (int i = 0; i < 4; ++i) v[i] = ((const float4*)xr)[i];
  float amax = 0.f;
#pragma unroll
  for (int i = 0; i < 4; ++i)
    amax = fmaxf(amax, fmaxf(fmaxf(fabsf(v[i].x), fabsf(v[i].y)),
                             fmaxf(fabsf(v[i].z), fabsf(v[i].w))));
#pragma unroll
  for (int off = 32; off; off >>= 1) amax = fmaxf(amax, __shfl_xor(amax, off, 64));
  __shared__ float wmax[4];
  if ((t & 63) == 0) wmax[t >> 6] = amax;
  __syncthreads();
  amax = fmaxf(fmaxf(wmax[0], wmax[1]), fmaxf(wmax[2], wmax[3]));
  const float inv = 127.0f / amax;
  if (t == 0) sxr[m] = amax / 127.0f;
  unsigned d[4];
#pragma unroll
  for (int i = 0; i < 4; ++i) {
    int q0 = (int)rintf(v[i].x * inv), q1 = (int)rintf(v[i].y * inv);
    int q2 = (int)rintf(v[i].z * inv), q3 = (int)rintf(v[i].w * inv);
    d[i] = (q0 & 0xff) | ((q1 & 0xff) << 8) | ((q2 & 0xff) << 16) | ((q3 & 0xff) << 24);
  }
  const int k32 = t >> 1, kg = t & 1;
  const int mtile = m >> 8, mm = m & 255, m32 = mm >> 5, r = mm & 31;
  int4* dst = (int4*)(A8S + ((size_t)(mtile * 128 + k32)) * 8192 + m32 * 1024 + kg * 512 + r * 16);
  *dst = make_int4(d[0], d[1], d[2], d[3]);
}

// ---- pre-pass 2: W requant to per-column scale, staged-tile order ----
// B8S = [ntile256 64][k32 128][n32 8][kg 2][col 32][16B]
__global__ __launch_bounds__(256) void pack_w8(const int* __restrict__ qs,
                                               const float* __restrict__ scales,
                                               char* __restrict__ B8S,
                                               float* __restrict__ swc) {
  const int o = blockIdx.x * 4 + (threadIdx.x >> 6);
  const int l = threadIdx.x & 63;
  const float s0 = scales[(size_t)o * NBLK_Q + l];
  const float s1 = scales[(size_t)o * NBLK_Q + 64 + l];
  float S = fmaxf(s0, s1);
#pragma unroll
  for (int off = 32; off; off >>= 1) S = fmaxf(S, __shfl_xor(S, off, 64));
  if (l == 0) swc[o] = S;
  const float rS = 1.0f / S;
  const int nt = o >> 8, col = o & 255, n32 = col >> 5, c = col & 31;
#pragma unroll
  for (int h = 0; h < 2; ++h) {
    const int nb = l + 64 * h;
    const float ratio = ((h == 0) ? s0 : s1) * rS;
    const int4* q = (const int4*)(qs + ((size_t)o * NBLK_Q + nb) * 32);
    unsigned d[8];
#pragma unroll
    for (int g = 0; g < 8; ++g) {
      int4 v = q[g];
      int a0 = (int)rintf((float)v.x * ratio);
      int a1 = (int)rintf((float)v.y * ratio);
      int a2 = (int)rintf((float)v.z * ratio);
      int a3 = (int)rintf((float)v.w * ratio);
      d[g] = (a0 & 0xff) | ((a1 & 0xff) << 8) | ((a2 & 0xff) << 16) | ((a3 & 0xff) << 24);
    }
    char* dst = B8S + ((size_t)(nt * 128 + nb)) * 8192 + n32 * 1024 + c * 16;
    ((int4*)dst)[0] = make_int4(d[0], d[1], d[2], d[3]);
    ((int4*)(dst + 512))[0] = make_int4(d[4], d[5], d[6], d[7]);
  }
}

// ---- main GEMM: NO LDS, NO barriers — all operands global(L1/L2)->registers ----
// 256x256 block (8 waves 2Mx4N), per-wave 128x64 = 4x2 of 32x32, BK=32,
// 8 mfma_i32_32x32x32_i8 per step. Staged layouts make every fragment a
// coalesced 1KB load (addr = base + kt*8192 + frag*1024 + l*16): per wave per
// step 4 A-loads (one 4KB contiguous region) + 2 B-loads (2KB contiguous).
// A is shared by 4 waves, B by 2 -> L1 (32KB) serves the duplicates (distinct
// working set 16KB/step); full-L2 fallback is 6.3GB device = 182us, still
// under target. DS pipe + barriers + lgkm + lockstep (the 768cy/step cost
// every R10-R16 variant paid) are GONE; waves drift freely, data-return
// latency hides under depth-2 ILP + 2 waves/SIMD.
// Pipeline: F(t) = 6 frag-loads of tile t. Prologue issues F0,F1 (12 in
// flight). Step kt: WAITVM(6) [F(kt) landed; F(kt+1) flies] -> 8 MFMA on cur
// set -> reload cur regs with F(kt+2) (WAR-safe: program order) -> advance
// pointers by 8192 unless target would pass tile 127 (clamped tail: dup
// loads of tile 127 land in regs never consumed). vmcnt never 0. Named reg
// sets, unroll-2 (rule #20). No cross-wave hazards exist in this structure.
// Grid: XCD-partitioned (FETCH 295MB proven): XCD x owns mtiles {2x,2x+1}.
__global__ __launch_bounds__(512, 2) void gemm_i8(
    const char* __restrict__ A8S, const char* __restrict__ B8S,
    const float* __restrict__ sxr, const float* __restrict__ swc,
    const float* __restrict__ bias, float* __restrict__ C) {
  const int tid = threadIdx.x;
  const int w = tid >> 6;
  const int l = tid & 63;
  const int wm = w >> 2;  // 0..1
  const int wn = w & 3;   // 0..3

  const int bid = blockIdx.x;
  const int xcd = bid & 7;
  const int k = bid >> 3;
  const int mtile = xcd * 2 + (k & 1);
  const int ntile = k >> 1;
  const int brow = mtile * BM;
  const int bcol = ntile * BN;

  // per-wave fragment base pointers (each instr = coalesced 1KB)
  const char* pA = A8S + (size_t)mtile * 1048576 + wm * 4096 + l * 16;
  const char* pB = B8S + (size_t)ntile * 1048576 + wn * 2048 + l * 16;

  i32x16 acc[4][2] = {};
  i32x4 xa0, xa1, xa2, xa3, xb0, xb1;  // frag set X
  i32x4 ya0, ya1, ya2, ya3, yb0, yb1;  // frag set Y

  // ---- prologue: issue F0 -> X, F1 -> Y (12 loads in flight) ----
  xa0 = *(const i32x4*)(pA);
  xa1 = *(const i32x4*)(pA + 1024);
  xa2 = *(const i32x4*)(pA + 2048);
  xa3 = *(const i32x4*)(pA + 3072);
  xb0 = *(const i32x4*)(pB);
  xb1 = *(const i32x4*)(pB + 1024);
  ya0 = *(const i32x4*)(pA + 8192);
  ya1 = *(const i32x4*)(pA + 8192 + 1024);
  ya2 = *(const i32x4*)(pA + 8192 + 2048);
  ya3 = *(const i32x4*)(pA + 8192 + 3072);
  yb0 = *(const i32x4*)(pB + 8192);
  yb1 = *(const i32x4*)(pB + 8192 + 1024);
  pA += 2 * 8192;  // next target: tile 2
  pB += 2 * 8192;

#define STEP(KT, A0, A1, A2, A3, B0, B1)                                       \
  do {                                                                         \
    WAITVM(6); /* F(KT) landed; F(KT+1)'s 6 still fly */                       \
    SFENCE();                                                                  \
    __builtin_amdgcn_s_setprio(1);                                             \
    acc[0][0] = __builtin_amdgcn_mfma_i32_32x32x32_i8(A0, B0, acc[0][0], 0, 0, 0); \
    acc[0][1] = __builtin_amdgcn_mfma_i32_32x32x32_i8(A0, B1, acc[0][1], 0, 0, 0); \
    acc[1][0] = __builtin_amdgcn_mfma_i32_32x32x32_i8(A1, B0, acc[1][0], 0, 0, 0); \
    acc[1][1] = __builtin_amdgcn_mfma_i32_32x32x32_i8(A1, B1, acc[1][1], 0, 0, 0); \
    acc[2][0] = __builtin_amdgcn_mfma_i32_32x32x32_i8(A2, B0, acc[2][0], 0, 0, 0); \
    acc[2][1] = __builtin_amdgcn_mfma_i32_32x32x32_i8(A2, B1, acc[2][1], 0, 0, 0); \
    acc[3][0] = __builtin_amdgcn_mfma_i32_32x32x32_i8(A3, B0, acc[3][0], 0, 0, 0); \
    acc[3][1] = __builtin_amdgcn_mfma_i32_32x32x32_i8(A3, B1, acc[3][1], 0, 0, 0); \
    __builtin_amdgcn_s_setprio(0);                                             \
    SFENCE();                                                                  \
    /* reload this set with F(KT+2) (regs just consumed; WAR via prog order) */\
    A0 = *(const i32x4*)(pA);                                                  \
    A1 = *(const i32x4*)(pA + 1024);                                           \
    A2 = *(const i32x4*)(pA + 2048);                                           \
    A3 = *(const i32x4*)(pA + 3072);                                           \
    B0 = *(const i32x4*)(pB);                                                  \
    B1 = *(const i32x4*)(pB + 1024);                                           \
    {                                                                          \
      const int adv = ((KT) + 3 <= KSTEPS - 1) ? 8192 : 0;                     \
      pA += adv;                                                               \
      pB += adv;                                                               \
    }                                                                          \
    SFENCE();                                                                  \
  } while (0)

  for (int kt = 0; kt < KSTEPS; kt += 2) {
    STEP(kt, xa0, xa1, xa2, xa3, xb0, xb1);
    STEP(kt + 1, ya0, ya1, ya2, ya3, yb0, yb1);
  }
#undef STEP

  WAITVM(0);  // drain tail loads (dead regs) before exit
  SFENCE();

  // epilogue: 32x32 C/D layout col = lane&31, row = (reg&3)+8*(reg>>2)+4*(lane>>5)
#pragma unroll
  for (int i = 0; i < 4; ++i) {
    const int rbx = brow + wm * 128 + i * 32 + 4 * (l >> 5);
#pragma unroll
    for (int j = 0; j < 2; ++j) {
      const int col = bcol + wn * 64 + j * 32 + (l & 31);
      const float Sw = swc[col];
      const float bv = bias[col];
#pragma unroll
      for (int r = 0; r < 16; ++r) {
        const int row = rbx + (r & 3) + 8 * (r >> 2);
        C[(size_t)row * N_DIM + col] = (float)acc[i][j][r] * (sxr[row] * Sw) + bv;
      }
    }
  }
}

// ---- fallback (ws too small): exact fp32, slow but correct ----
__global__ void naive_gemm(const float* __restrict__ x, const int* __restrict__ qs,
                           const float* __restrict__ scales, const float* __restrict__ bias,
                           float* __restrict__ y) {
  size_t idx = (size_t)blockIdx.x * 256 + threadIdx.x;
  if (idx >= (size_t)M_DIM * N_DIM) return;
  int o = (int)(idx % N_DIM);
  size_t m = idx / N_DIM;
  const float* xr = x + m * K_DIM;
  const int* q = qs + (size_t)o * K_DIM;
  const float* sc = scales + (size_t)o * NBLK_Q;
  float sum = 0.f;
  for (int nb = 0; nb < NBLK_Q; ++nb) {
    float s = sc[nb];
    float bs = 0.f;
#pragma unroll 8
    for (int b = 0; b < 32; ++b) bs += xr[nb * 32 + b] * (float)q[nb * 32 + b];
    sum += s * bs;
  }
  y[idx] = sum + bias[o];
}

extern "C" void kernel_launch(void* const* d_in, const int* in_sizes, int n_in,
                              void* d_out, int out_size, void* d_ws, size_t ws_size,
                              hipStream_t stream) {
  const float* x = (const float*)d_in[0];
  const int* qs = (const int*)d_in[1];
  const float* scales = (const float*)d_in[2];
  const float* bias = (const float*)d_in[3];
  float* y = (float*)d_out;

  const size_t A8_bytes = (size_t)M_DIM * K_DIM;   // 16 MB
  const size_t B8_bytes = (size_t)N_DIM * K_DIM;   // 64 MB
  const size_t SX_bytes = (size_t)M_DIM * 4;
  const size_t SW_bytes = (size_t)N_DIM * 4;

  if (ws_size < A8_bytes + B8_bytes + SX_bytes + SW_bytes) {
    size_t total = (size_t)M_DIM * N_DIM;
    naive_gemm<<<(unsigned)((total + 255) / 256), 256, 0, stream>>>(x, qs, scales, bias, y);
    return;
  }

  char* A8S = (char*)d_ws;
  char* B8S = A8S + A8_bytes;
  float* sxr = (float*)(B8S + B8_bytes);
  float* swc = (float*)((char*)sxr + SX_bytes);

  quant_x<<<M_DIM, 256, 0, stream>>>(x, A8S, sxr);
  pack_w8<<<N_DIM / 4, 256, 0, stream>>>(qs, scales, B8S, swc);
  gemm_i8<<<(M_DIM / BM) * (N_DIM / BN), 512, 0, stream>>>(A8S, B8S, sxr, swc, bias, y);
}